// Round 1
// baseline (382.699 us; speedup 1.0000x reference)
//
#include <hip/hip_runtime.h>

#define NUM_CLASSES 80
#define MAX_O 16
#define RPB 256  // rows per block in the fused loss kernel (== blockDim.x)

// ---------------- device helpers ----------------

// balanced_l1: R_ALPHA=0.5, R_GAMMA=1.5, R_BETA=0.11, b = e^3 - 1
__device__ __forceinline__ float bl1f(float diff) {
  const float bc = 19.085537f;  // float32(e^3 - 1)
  float d = fabsf(diff);
  if (d < 0.11f) {
    return 0.5f / bc * (bc * d + 1.0f) * __logf(1.0f + bc * d / 0.11f) - 0.5f * d;
  }
  return 1.5f * d + 1.5f / bc - 0.5f * 0.11f;
}

// focal with t=0: (max(l,0)+log1p(exp(-|l|))) * 0.75 * sigmoid(l)
__device__ __forceinline__ float focal0(float l) {
  float a = fabsf(l);
  float q = __expf(-a);
  float lp = __logf(1.0f + q);
  float r = __builtin_amdgcn_rcpf(1.0f + q);
  float p = (l >= 0.0f) ? r : q * r;
  return (fmaxf(l, 0.0f) + lp) * (0.75f * p);
}

// focal(l, t=1) - focal(l, t=0): correction for the single positive class
__device__ __forceinline__ float focal_delta(float l) {
  float a = fabsf(l);
  float q = __expf(-a);
  float lp = __logf(1.0f + q);
  float r = __builtin_amdgcn_rcpf(1.0f + q);
  float p = (l >= 0.0f) ? r : q * r;
  float f1 = (fmaxf(l, 0.0f) - l + lp) * (0.25f * (1.0f - p));
  float f0 = (fmaxf(l, 0.0f) + lp) * (0.75f * p);
  return f1 - f0;
}

// ---------------- kernel 0: zero accumulators + argmax keys ----------------

__global__ void init_kernel(double* __restrict__ acc,
                            unsigned long long* __restrict__ gkey, int nkey) {
  int i = blockIdx.x * blockDim.x + threadIdx.x;
  if (i < nkey) gkey[i] = 0ull;
  if (i == 0) { acc[0] = 0.0; acc[1] = 0.0; acc[2] = 0.0; }
}

// ---------------- kernel 1a: matching, parallel over priors ----------------

__global__ __launch_bounds__(256)
void match_partial_kernel(const float* __restrict__ priors,
                          const float* __restrict__ targets,
                          float* __restrict__ bto,
                          int* __restrict__ bti,
                          unsigned long long* __restrict__ gkey,
                          int P, int O) {
  int b = blockIdx.y;
  int tid = threadIdx.x;

  __shared__ float s_t[MAX_O][4];
  __shared__ float s_area[MAX_O];
  if (tid < O) {
    const float* t = targets + ((size_t)b * O + tid) * 5;
    float x1 = t[0], y1 = t[1], x2 = t[2], y2 = t[3];
    s_t[tid][0] = x1; s_t[tid][1] = y1; s_t[tid][2] = x2; s_t[tid][3] = y2;
    s_area[tid] = (x2 - x1) * (y2 - y1);
  }
  __syncthreads();

  float bov[MAX_O];
  unsigned bpi[MAX_O];
#pragma unroll
  for (int t = 0; t < MAX_O; ++t) { bov[t] = -1.0f; bpi[t] = 0u; }

  for (int p = blockIdx.x * blockDim.x + tid; p < P;
       p += gridDim.x * blockDim.x) {
    const float* pr = priors + (size_t)p * 4;
    float cx = pr[0], cy = pr[1], w = pr[2], h = pr[3];
    float px1 = cx - 0.5f * w, py1 = cy - 0.5f * h;
    float px2 = cx + 0.5f * w, py2 = cy + 0.5f * h;
    float parea = (px2 - px1) * (py2 - py1);

    float best = -1.0f;
    int bestt = 0;
#pragma unroll
    for (int t = 0; t < MAX_O; ++t) {
      if (t < O) {
        float lx = fmaxf(s_t[t][0], px1);
        float ly = fmaxf(s_t[t][1], py1);
        float rx = fminf(s_t[t][2], px2);
        float ry = fminf(s_t[t][3], py2);
        float iw = fmaxf(rx - lx, 0.0f);
        float ih = fmaxf(ry - ly, 0.0f);
        float inter = iw * ih;
        float ov = inter / (s_area[t] + parea - inter);
        if (ov > best) { best = ov; bestt = t; }             // first-max axis=0
        if (ov > bov[t]) { bov[t] = ov; bpi[t] = (unsigned)p; }
      }
    }
    bto[(size_t)b * P + p] = best;
    bti[(size_t)b * P + p] = bestt;
  }

  int lane = tid & 63;
#pragma unroll
  for (int t = 0; t < MAX_O; ++t) {
    if (t < O) {
      unsigned long long key = (bov[t] >= 0.0f)
          ? (((unsigned long long)__float_as_uint(bov[t]) << 32) |
             (unsigned long long)(0xFFFFFFFFu - bpi[t]))
          : 0ull;
      for (int o = 32; o > 0; o >>= 1) {
        unsigned long long other = __shfl_xor(key, o, 64);
        if (other > key) key = other;
      }
      if (lane == 0 && key != 0ull)
        atomicMax(&gkey[(size_t)b * O + t], key);
    }
  }
}

// ---------------- kernel 1b: override ----------------

__global__ void match_override_kernel(const unsigned long long* __restrict__ gkey,
                                      float* __restrict__ bto,
                                      int* __restrict__ bti,
                                      int P, int O) {
  int b = blockIdx.x;
  if (threadIdx.x == 0) {
    for (int t = 0; t < O; ++t) {
      unsigned p = 0xFFFFFFFFu - (unsigned)(gkey[(size_t)b * O + t] & 0xFFFFFFFFull);
      bto[(size_t)b * P + p] = 2.0f;
      bti[(size_t)b * P + p] = t;
    }
  }
}

// ---------------- kernel 2: fused loc + conf loss ----------------
// Each block owns RPB contiguous rows.
// Phase 1: one thread per row — loc loss + pos count + row class into LDS.
// Phase 2: grid over RPB*10 8-wide chunks of conf logits; row class comes
// from LDS (no global rowcls round-trip). All elements computed as t=0;
// the single positive class gets a rare focal_delta correction.

__global__ __launch_bounds__(256)
void fused_loss_kernel(const float* __restrict__ loc_data,
                       const float4* __restrict__ conf4,
                       const float* __restrict__ priors,
                       const float* __restrict__ targets,
                       const float* __restrict__ bto,
                       const int* __restrict__ bti,
                       double* __restrict__ acc,
                       int B, int P, int O, int BP) {
  __shared__ int s_cls[RPB];
  __shared__ double sbuf_l[4];
  __shared__ double sbuf_n[4];
  __shared__ double sbuf_c[4];

  int tid = threadIdx.x;
  int row0 = blockIdx.x * RPB;
  int row = row0 + tid;

  float lsum = 0.0f;
  float nsum = 0.0f;
  int cls = -1;

  // ----- phase 1: per-row loc loss + class -----
  if (row < BP) {
    float ov = bto[row];
    if (ov >= 0.5f) {
      nsum = 1.0f;
      int b = row / P;
      int p = row - b * P;
      int t = bti[row];
      const float* tr = targets + ((size_t)b * O + t) * 5;
      float x1 = tr[0], y1 = tr[1], x2 = tr[2], y2 = tr[3];
      cls = (int)tr[4] + 1;
      const float* pr = priors + (size_t)p * 4;
      float cx = pr[0], cy = pr[1], w = pr[2], h = pr[3];
      float gcx = ((x1 + x2) * 0.5f - cx) / (0.1f * w);
      float gcy = ((y1 + y2) * 0.5f - cy) / (0.1f * h);
      float gw = __logf((x2 - x1) / w) * 5.0f;   // /0.2
      float gh = __logf((y2 - y1) / h) * 5.0f;
      const float* ld = loc_data + (size_t)row * 4;
      lsum = bl1f(ld[0] - gcx) + bl1f(ld[1] - gcy) +
             bl1f(ld[2] - gw) + bl1f(ld[3] - gh);
    } else {
      cls = (ov < 0.4f) ? 0 : -1;
    }
  }
  s_cls[tid] = cls;
  __syncthreads();

  // ----- phase 2: conf loss over this block's RPB rows -----
  float csum = 0.0f;
#pragma unroll 2
  for (int i = 0; i < 10; ++i) {       // RPB*10 chunks / 256 threads
    int chunk = tid + (i << 8);        // 0 .. RPB*10-1
    int rl = chunk / 10;               // local row (magic-mul)
    int c = chunk - rl * 10;           // 8-elem chunk within row
    int r = row0 + rl;
    if (r < BP) {
      int rcls = s_cls[rl];            // LDS broadcast, no global dep
      const float4* base = conf4 + (size_t)r * 20 + (size_t)c * 2;
      float4 u = base[0];
      float4 v = base[1];
      float s = focal0(u.x) + focal0(u.y) + focal0(u.z) + focal0(u.w) +
                focal0(v.x) + focal0(v.y) + focal0(v.z) + focal0(v.w);
      if (rcls > 0) {
        int j = rcls - 1 - c * 8;      // position of positive class in chunk
        if ((unsigned)j < 8u) {
          float l = (j < 4) ? (j == 0 ? u.x : j == 1 ? u.y : j == 2 ? u.z : u.w)
                            : (j == 4 ? v.x : j == 5 ? v.y : j == 6 ? v.z : v.w);
          s += focal_delta(l);
        }
      }
      csum += (rcls >= 0) ? s : 0.0f;
    }
  }

  // ----- reductions: one atomic per accumulator per block -----
  for (int o = 32; o > 0; o >>= 1) {
    lsum += __shfl_down(lsum, o, 64);
    nsum += __shfl_down(nsum, o, 64);
    csum += __shfl_down(csum, o, 64);
  }
  int lane = tid & 63, wid = tid >> 6;
  if (lane == 0) {
    sbuf_l[wid] = (double)lsum;
    sbuf_n[wid] = (double)nsum;
    sbuf_c[wid] = (double)csum;
  }
  __syncthreads();
  if (tid == 0) {
    atomicAdd(&acc[0], sbuf_l[0] + sbuf_l[1] + sbuf_l[2] + sbuf_l[3]);
    atomicAdd(&acc[2], sbuf_n[0] + sbuf_n[1] + sbuf_n[2] + sbuf_n[3]);
    atomicAdd(&acc[1], sbuf_c[0] + sbuf_c[1] + sbuf_c[2] + sbuf_c[3]);
  }
}

// ---------------- kernel 3: finalize ----------------

__global__ void final_kernel(const double* __restrict__ acc,
                             float* __restrict__ out) {
  if (threadIdx.x == 0) {
    double pn = acc[2] > 1.0 ? acc[2] : 1.0;
    out[0] = (float)(acc[0] / (pn * 4.0));
    out[1] = (float)(acc[1] / pn);
  }
}

// ---------------- launch ----------------

extern "C" void kernel_launch(void* const* d_in, const int* in_sizes, int n_in,
                              void* d_out, int out_size, void* d_ws, size_t ws_size,
                              hipStream_t stream) {
  const float* loc_data  = (const float*)d_in[0];
  const float* conf_data = (const float*)d_in[1];
  const float* priors    = (const float*)d_in[2];
  const float* targets   = (const float*)d_in[3];
  float* out = (float*)d_out;

  int P  = in_sizes[2] / 4;        // 16384
  int BP = in_sizes[0] / 4;        // B*P
  int B  = BP / P;                 // 32
  int O  = in_sizes[3] / (B * 5);  // 16

  // ws layout: bto (BP f32) | bti (BP i32) | gkey (B*O u64) | acc (3 f64)
  float* bto    = (float*)d_ws;
  int* bti      = (int*)((char*)d_ws + (size_t)BP * 4);
  unsigned long long* gkey =
      (unsigned long long*)((char*)d_ws + (size_t)BP * 8);
  double* acc   = (double*)((char*)d_ws + (size_t)BP * 8 + (size_t)B * O * 8);

  int nkey = B * O;
  hipLaunchKernelGGL(init_kernel, dim3(1), dim3(1024), 0, stream, acc, gkey, nkey);

  int nbx = (P + 255) / 256;
  hipLaunchKernelGGL(match_partial_kernel, dim3(nbx, B), dim3(256), 0, stream,
                     priors, targets, bto, bti, gkey, P, O);
  hipLaunchKernelGGL(match_override_kernel, dim3(B), dim3(64), 0, stream,
                     gkey, bto, bti, P, O);
  int nblk = (BP + RPB - 1) / RPB;
  hipLaunchKernelGGL(fused_loss_kernel, dim3(nblk), dim3(256), 0, stream,
                     loc_data, (const float4*)conf_data, priors, targets,
                     bto, bti, acc, B, P, O, BP);
  hipLaunchKernelGGL(final_kernel, dim3(1), dim3(64), 0, stream, acc, out);
}

// Round 2
// 302.829 us; speedup vs baseline: 1.2637x; 1.2637x over previous
//
#include <hip/hip_runtime.h>

#define NUM_CLASSES 80
#define MAX_O 16
#define RPB 256      // rows per block in the fused loss kernel (== blockDim.x)
#define MATCH_GX 8   // grid.x of match kernel (grid-stride over priors)

// ---------------- device helpers ----------------

// balanced_l1: R_ALPHA=0.5, R_GAMMA=1.5, R_BETA=0.11, b = e^3 - 1
__device__ __forceinline__ float bl1f(float diff) {
  const float bc = 19.085537f;  // float32(e^3 - 1)
  float d = fabsf(diff);
  if (d < 0.11f) {
    return 0.5f / bc * (bc * d + 1.0f) * __logf(1.0f + bc * d / 0.11f) - 0.5f * d;
  }
  return 1.5f * d + 1.5f / bc - 0.5f * 0.11f;
}

// focal(l, t=0) = 0.75 * softplus(l) * sigmoid(l), z = e^l:
//   softplus = log(1+z), sigmoid = z/(1+z). 3 trans + 4 VALU, no sign select.
__device__ __forceinline__ float focal0(float l) {
  float z = __expf(l);
  float r = __builtin_amdgcn_rcpf(1.0f + z);
  float sp = __logf(1.0f + z);
  return 0.75f * sp * (z * r);
}

// focal(l,1) - focal(l,0) = 0.25*(sp - l)/(1+z) - 0.75*sp*z/(1+z)
__device__ __forceinline__ float focal_delta(float l) {
  float z = __expf(l);
  float r = __builtin_amdgcn_rcpf(1.0f + z);
  float sp = __logf(1.0f + z);
  return (0.25f * (sp - l)) * r - 0.75f * sp * (z * r);
}

// ---------------- kernel 0: zero accumulators + argmax keys ----------------

__global__ void init_kernel(double* __restrict__ acc,
                            unsigned long long* __restrict__ gkey, int nkey) {
  int i = blockIdx.x * blockDim.x + threadIdx.x;
  if (i < nkey) gkey[i] = 0ull;
  if (i == 0) { acc[0] = 0.0; acc[1] = 0.0; acc[2] = 0.0; }
}

// ---------------- kernel 1a: matching, parallel over priors ----------------
// grid (MATCH_GX, B). Block-level LDS reduction of argmax keys before the
// global atomicMax: 8 blocks/batch * 16 targets = 128 atomics per batch
// (was 64 blocks * 4 waves * 16 = 4096).

__global__ __launch_bounds__(256)
void match_partial_kernel(const float4* __restrict__ priors4,
                          const float* __restrict__ targets,
                          float* __restrict__ bto,
                          int* __restrict__ bti,
                          unsigned long long* __restrict__ gkey,
                          int P, int O) {
  int b = blockIdx.y;
  int tid = threadIdx.x;

  __shared__ float s_t[MAX_O][4];
  __shared__ float s_area[MAX_O];
  __shared__ unsigned long long s_key[4][MAX_O];
  if (tid < O) {
    const float* t = targets + ((size_t)b * O + tid) * 5;
    float x1 = t[0], y1 = t[1], x2 = t[2], y2 = t[3];
    s_t[tid][0] = x1; s_t[tid][1] = y1; s_t[tid][2] = x2; s_t[tid][3] = y2;
    s_area[tid] = (x2 - x1) * (y2 - y1);
  }
  __syncthreads();

  float bov[MAX_O];
  unsigned bpi[MAX_O];
#pragma unroll
  for (int t = 0; t < MAX_O; ++t) { bov[t] = -1.0f; bpi[t] = 0u; }

  for (int p = blockIdx.x * blockDim.x + tid; p < P;
       p += MATCH_GX * blockDim.x) {
    float4 pr = priors4[p];
    float px1 = pr.x - 0.5f * pr.z, py1 = pr.y - 0.5f * pr.w;
    float px2 = pr.x + 0.5f * pr.z, py2 = pr.y + 0.5f * pr.w;
    float parea = (px2 - px1) * (py2 - py1);

    float best = -1.0f;
    int bestt = 0;
#pragma unroll
    for (int t = 0; t < MAX_O; ++t) {
      if (t < O) {
        float lx = fmaxf(s_t[t][0], px1);
        float ly = fmaxf(s_t[t][1], py1);
        float rx = fminf(s_t[t][2], px2);
        float ry = fminf(s_t[t][3], py2);
        float iw = fmaxf(rx - lx, 0.0f);
        float ih = fmaxf(ry - ly, 0.0f);
        float inter = iw * ih;
        float ov = inter / (s_area[t] + parea - inter);
        if (ov > best) { best = ov; bestt = t; }             // first-max axis=0
        if (ov > bov[t]) { bov[t] = ov; bpi[t] = (unsigned)p; }
      }
    }
    bto[(size_t)b * P + p] = best;
    bti[(size_t)b * P + p] = bestt;
  }

  int lane = tid & 63, wid = tid >> 6;
#pragma unroll
  for (int t = 0; t < MAX_O; ++t) {
    if (t < O) {
      unsigned long long key = (bov[t] >= 0.0f)
          ? (((unsigned long long)__float_as_uint(bov[t]) << 32) |
             (unsigned long long)(0xFFFFFFFFu - bpi[t]))
          : 0ull;
      for (int o = 32; o > 0; o >>= 1) {
        unsigned long long other = __shfl_xor(key, o, 64);
        if (other > key) key = other;
      }
      if (lane == 0) s_key[wid][t] = key;
    }
  }
  __syncthreads();
  if (tid < O) {
    unsigned long long k0 = s_key[0][tid] > s_key[1][tid] ? s_key[0][tid] : s_key[1][tid];
    unsigned long long k1 = s_key[2][tid] > s_key[3][tid] ? s_key[2][tid] : s_key[3][tid];
    unsigned long long k = k0 > k1 ? k0 : k1;
    if (k != 0ull) atomicMax(&gkey[(size_t)b * O + tid], k);
  }
}

// ---------------- kernel 1b: override ----------------
// Serial per-batch on purpose: later t must win on duplicate best-prior
// (matches reference .at[].set ordering).

__global__ void match_override_kernel(const unsigned long long* __restrict__ gkey,
                                      float* __restrict__ bto,
                                      int* __restrict__ bti,
                                      int P, int O) {
  int b = blockIdx.x;
  if (threadIdx.x == 0) {
    for (int t = 0; t < O; ++t) {
      unsigned p = 0xFFFFFFFFu - (unsigned)(gkey[(size_t)b * O + t] & 0xFFFFFFFFull);
      bto[(size_t)b * P + p] = 2.0f;
      bti[(size_t)b * P + p] = t;
    }
  }
}

// ---------------- kernel 2: fused loc + conf loss ----------------
// Each block owns RPB contiguous rows.
// Phase 1: one thread per row — loc loss + pos count + row class into LDS.
// Phase 2: all 20 float4 conf loads issued up front (max loads in flight —
// the round-1 profile showed 1.4 TB/s effective / 26% VALU: latency-bound),
// then fully-unrolled focal math consuming them in order.

__global__ __launch_bounds__(256)
void fused_loss_kernel(const float* __restrict__ loc_data,
                       const float4* __restrict__ conf4,
                       const float* __restrict__ priors,
                       const float* __restrict__ targets,
                       const float* __restrict__ bto,
                       const int* __restrict__ bti,
                       double* __restrict__ acc,
                       int B, int P, int O, int BP) {
  __shared__ int s_cls[RPB];
  __shared__ double sbuf_l[4];
  __shared__ double sbuf_n[4];
  __shared__ double sbuf_c[4];

  int tid = threadIdx.x;
  int row0 = blockIdx.x * RPB;
  int row = row0 + tid;

  float lsum = 0.0f;
  float nsum = 0.0f;
  int cls = -1;

  // ----- phase 1: per-row loc loss + class -----
  if (row < BP) {
    float ov = bto[row];
    if (ov >= 0.5f) {
      nsum = 1.0f;
      int b = row / P;
      int p = row - b * P;
      int t = bti[row];
      const float* tr = targets + ((size_t)b * O + t) * 5;
      float x1 = tr[0], y1 = tr[1], x2 = tr[2], y2 = tr[3];
      cls = (int)tr[4] + 1;
      const float* pr = priors + (size_t)p * 4;
      float cx = pr[0], cy = pr[1], w = pr[2], h = pr[3];
      float gcx = ((x1 + x2) * 0.5f - cx) / (0.1f * w);
      float gcy = ((y1 + y2) * 0.5f - cy) / (0.1f * h);
      float gw = __logf((x2 - x1) / w) * 5.0f;   // /0.2
      float gh = __logf((y2 - y1) / h) * 5.0f;
      const float* ld = loc_data + (size_t)row * 4;
      lsum = bl1f(ld[0] - gcx) + bl1f(ld[1] - gcy) +
             bl1f(ld[2] - gw) + bl1f(ld[3] - gh);
    } else {
      cls = (ov < 0.4f) ? 0 : -1;
    }
  }
  s_cls[tid] = cls;
  __syncthreads();

  // ----- phase 2: conf loss over this block's RPB rows -----
  float csum = 0.0f;
  if (row0 + RPB <= BP) {
    // full block: issue all 20 loads first, then compute
    const float4* base = conf4 + (size_t)row0 * 20;
    float4 U[10], V[10];
#pragma unroll
    for (int i = 0; i < 10; ++i) {
      int chunk = tid + (i << 8);
      U[i] = base[(size_t)chunk * 2];
      V[i] = base[(size_t)chunk * 2 + 1];
    }
#pragma unroll
    for (int i = 0; i < 10; ++i) {
      int chunk = tid + (i << 8);
      int rl = chunk / 10;             // magic-mul
      int c = chunk - rl * 10;
      int rcls = s_cls[rl];
      float4 u = U[i], v = V[i];
      float s = focal0(u.x) + focal0(u.y) + focal0(u.z) + focal0(u.w) +
                focal0(v.x) + focal0(v.y) + focal0(v.z) + focal0(v.w);
      if (rcls > 0) {
        int j = rcls - 1 - c * 8;      // position of positive class in chunk
        if ((unsigned)j < 8u) {
          float l = (j < 4) ? (j == 0 ? u.x : j == 1 ? u.y : j == 2 ? u.z : u.w)
                            : (j == 4 ? v.x : j == 5 ? v.y : j == 6 ? v.z : v.w);
          s += focal_delta(l);
        }
      }
      csum += (rcls >= 0) ? s : 0.0f;
    }
  } else {
    // tail block (not hit for the bench shape): guarded scalar path
    for (int i = 0; i < 10; ++i) {
      int chunk = tid + (i << 8);
      int rl = chunk / 10;
      int c = chunk - rl * 10;
      int r = row0 + rl;
      if (r < BP) {
        int rcls = s_cls[rl];
        const float4* base = conf4 + (size_t)r * 20 + (size_t)c * 2;
        float4 u = base[0];
        float4 v = base[1];
        float s = focal0(u.x) + focal0(u.y) + focal0(u.z) + focal0(u.w) +
                  focal0(v.x) + focal0(v.y) + focal0(v.z) + focal0(v.w);
        if (rcls > 0) {
          int j = rcls - 1 - c * 8;
          if ((unsigned)j < 8u) {
            float l = (j < 4) ? (j == 0 ? u.x : j == 1 ? u.y : j == 2 ? u.z : u.w)
                              : (j == 4 ? v.x : j == 5 ? v.y : j == 6 ? v.z : v.w);
            s += focal_delta(l);
          }
        }
        csum += (rcls >= 0) ? s : 0.0f;
      }
    }
  }

  // ----- reductions: one atomic per accumulator per block -----
  for (int o = 32; o > 0; o >>= 1) {
    lsum += __shfl_down(lsum, o, 64);
    nsum += __shfl_down(nsum, o, 64);
    csum += __shfl_down(csum, o, 64);
  }
  int lane = tid & 63, wid = tid >> 6;
  if (lane == 0) {
    sbuf_l[wid] = (double)lsum;
    sbuf_n[wid] = (double)nsum;
    sbuf_c[wid] = (double)csum;
  }
  __syncthreads();
  if (tid == 0) {
    atomicAdd(&acc[0], sbuf_l[0] + sbuf_l[1] + sbuf_l[2] + sbuf_l[3]);
    atomicAdd(&acc[2], sbuf_n[0] + sbuf_n[1] + sbuf_n[2] + sbuf_n[3]);
    atomicAdd(&acc[1], sbuf_c[0] + sbuf_c[1] + sbuf_c[2] + sbuf_c[3]);
  }
}

// ---------------- kernel 3: finalize ----------------

__global__ void final_kernel(const double* __restrict__ acc,
                             float* __restrict__ out) {
  if (threadIdx.x == 0) {
    double pn = acc[2] > 1.0 ? acc[2] : 1.0;
    out[0] = (float)(acc[0] / (pn * 4.0));
    out[1] = (float)(acc[1] / pn);
  }
}

// ---------------- launch ----------------

extern "C" void kernel_launch(void* const* d_in, const int* in_sizes, int n_in,
                              void* d_out, int out_size, void* d_ws, size_t ws_size,
                              hipStream_t stream) {
  const float* loc_data  = (const float*)d_in[0];
  const float* conf_data = (const float*)d_in[1];
  const float* priors    = (const float*)d_in[2];
  const float* targets   = (const float*)d_in[3];
  float* out = (float*)d_out;

  int P  = in_sizes[2] / 4;        // 16384
  int BP = in_sizes[0] / 4;        // B*P
  int B  = BP / P;                 // 32
  int O  = in_sizes[3] / (B * 5);  // 16

  // ws layout: bto (BP f32) | bti (BP i32) | gkey (B*O u64) | acc (3 f64)
  float* bto    = (float*)d_ws;
  int* bti      = (int*)((char*)d_ws + (size_t)BP * 4);
  unsigned long long* gkey =
      (unsigned long long*)((char*)d_ws + (size_t)BP * 8);
  double* acc   = (double*)((char*)d_ws + (size_t)BP * 8 + (size_t)B * O * 8);

  int nkey = B * O;
  hipLaunchKernelGGL(init_kernel, dim3(1), dim3(1024), 0, stream, acc, gkey, nkey);

  hipLaunchKernelGGL(match_partial_kernel, dim3(MATCH_GX, B), dim3(256), 0, stream,
                     (const float4*)priors, targets, bto, bti, gkey, P, O);
  hipLaunchKernelGGL(match_override_kernel, dim3(B), dim3(64), 0, stream,
                     gkey, bto, bti, P, O);
  int nblk = (BP + RPB - 1) / RPB;
  hipLaunchKernelGGL(fused_loss_kernel, dim3(nblk), dim3(256), 0, stream,
                     loc_data, (const float4*)conf_data, priors, targets,
                     bto, bti, acc, B, P, O, BP);
  hipLaunchKernelGGL(final_kernel, dim3(1), dim3(64), 0, stream, acc, out);
}